// Round 12
// baseline (164.262 us; speedup 1.0000x reference)
//
#include <hip/hip_runtime.h>
#include <hip/hip_bf16.h>

// B=2,T=64,V=32000,NH=32,HD=32. BT=128, M=4096 rows, D=32.
// Flash-attn formulation: Q=F (4096x32, pre-scaled by invt*log2e),
// K=V=vs (32000x32). S=Q.vs^T, P=exp2(S), out = P.vs / rowsum(P).
// 3 ordinary launches with cross-boundary overlap:
//  K1: prep chunks 0..499 (slices 0-7) + F + zero cnt      [HBM]
//  K2: s<8 blocks fused(slice s) || s>=8 blocks prep 500..999 [VALU || HBM]
//  K3: fused slices 8-15 + cnt-gated per-qp combine        [VALU]
#define NV      32000
#define MROWS   4096
#define NSLICE  16
#define PART_STRIDE 1056       // 32x32 acc + 32 lsum

typedef __attribute__((ext_vector_type(8))) short short8;
typedef __attribute__((ext_vector_type(16))) float f32x16;
typedef __attribute__((ext_vector_type(4))) float f32x4;

// ws layout (bytes):
//   vsb  [NV][32]        bf16 : 0          (2,048,000)
//   vstb [1000][32][32]  bf16 : 2,048,000  (2,048,000)  chunk-blocked transpose
//   Fb   [M][32]         bf16 : 4,096,000  (262,144)
//   part [2048][1056]    f32  : 4,358,144  (8,650,752)
//   cnt  [64] int             : 13,008,896
#define OFF_VSB  0
#define OFF_VSTB 2048000
#define OFF_FB   4096000
#define OFF_PART 4358144
#define OFF_CNT  13008896

static __device__ __forceinline__ unsigned pkbf(float lo, float hi) {
    union { __hip_bfloat162 h; unsigned u; } cv;
    cv.h.x = __float2bfloat16(lo);
    cv.h.y = __float2bfloat16(hi);
    return cv.u;
}
static __device__ __forceinline__ f32x4 ntload(const float* p) {
    return __builtin_nontemporal_load((const f32x4*)p);
}

// ---- prep one 32-v chunk: vs sums -> bf16 vsb + chunk-blocked vstb ----
static __device__ __forceinline__ void prep_chunk(int blk, const float* __restrict__ emb,
                                                  unsigned short* __restrict__ vsb,
                                                  unsigned short* __restrict__ vstb,
                                                  float* __restrict__ smem, int tid) {
    const int vbase = blk * 32;
    const int wave = tid >> 6, lane = tid & 63;
    float (*lds)[33] = (float(*)[33])smem;
    for (int vl = wave; vl < 32; vl += 4) {
        const float* p = emb + (size_t)(vbase + vl) * 1024 + lane * 4;
        f32x4 a0 = ntload(p), a1 = ntload(p + 256), a2 = ntload(p + 512), a3 = ntload(p + 768);
        float s0 = a0.x + a0.y + a0.z + a0.w;
        float s1 = a1.x + a1.y + a1.z + a1.w;
        float s2 = a2.x + a2.y + a2.z + a2.w;
        float s3 = a3.x + a3.y + a3.z + a3.w;
        s0 += __shfl_xor(s0, 1, 64); s0 += __shfl_xor(s0, 2, 64); s0 += __shfl_xor(s0, 4, 64);
        s1 += __shfl_xor(s1, 1, 64); s1 += __shfl_xor(s1, 2, 64); s1 += __shfl_xor(s1, 4, 64);
        s2 += __shfl_xor(s2, 1, 64); s2 += __shfl_xor(s2, 2, 64); s2 += __shfl_xor(s2, 4, 64);
        s3 += __shfl_xor(s3, 1, 64); s3 += __shfl_xor(s3, 2, 64); s3 += __shfl_xor(s3, 4, 64);
        if ((lane & 7) == 0) {
            int hb = lane >> 3;
            lds[vl][hb]      = s0;
            lds[vl][hb + 8]  = s1;
            lds[vl][hb + 16] = s2;
            lds[vl][hb + 24] = s3;
        }
    }
    __syncthreads();
    {
        int v = tid >> 3, h = (tid & 7) * 4;
        unsigned o[2];
        o[0] = pkbf(lds[v][h],     lds[v][h + 1]);
        o[1] = pkbf(lds[v][h + 2], lds[v][h + 3]);
        *(uint2*)(vsb + (size_t)(vbase + v) * 32 + h) = *(uint2*)o;
    }
    {
        int h = tid >> 3, vi = (tid & 7) * 4;
        unsigned o[2];
        o[0] = pkbf(lds[vi][h],     lds[vi + 1][h]);
        o[1] = pkbf(lds[vi + 2][h], lds[vi + 3][h]);
        *(uint2*)(vstb + (size_t)blk * 1024 + h * 32 + vi) = *(uint2*)o;
    }
}

// ---- prep one 256-elem F chunk (pre-scaled by invt*log2e) ----
static __device__ __forceinline__ void prep_F(int fblk, const float* __restrict__ x,
                                              const float* __restrict__ W,
                                              const float* __restrict__ bias,
                                              const float* __restrict__ temps,
                                              unsigned short* __restrict__ Fb, int tid) {
    int t = fblk * 256 + tid;   // t = frow*32 + d
    int frow = t >> 5, d = t & 31;
    const float4* xp = (const float4*)(x + (size_t)frow * 32);
    const float4* wp = (const float4*)(W + (size_t)d * 32);
    float s = bias[d];
#pragma unroll
    for (int i = 0; i < 8; ++i) {
        float4 xv = xp[i];
        float4 wv = wp[i];
        s += xv.x * wv.x + xv.y * wv.y + xv.z * wv.z + xv.w * wv.w;
    }
    float sc = 1.44269504088896f / fmaxf(temps[frow & 31], 0.1f);
    __hip_bfloat16 bv = __float2bfloat16(s * sc);
    Fb[t] = *reinterpret_cast<unsigned short*>(&bv);
}

// ---- fused flash for (qp, s): identical inner loop to round 10 ----
#define TILE(QA, QB, OACC, LSUM) do {                                              \
    f32x16 sa;                                                                     \
    _Pragma("unroll")                                                              \
    for (int r = 0; r < 16; ++r) sa[r] = 0.f;                                      \
    sa = __builtin_amdgcn_mfma_f32_32x32x16_bf16(va0, QA, sa, 0, 0, 0);            \
    sa = __builtin_amdgcn_mfma_f32_32x32x16_bf16(va1, QB, sa, 0, 0, 0);            \
    _Pragma("unroll")                                                              \
    for (int r = 0; r < 16; ++r) sa[r] = __builtin_amdgcn_exp2f(sa[r]);            \
    {                                                                              \
        float t0 = sa[0] + sa[1],   t1 = sa[2] + sa[3];                            \
        float t2 = sa[4] + sa[5],   t3 = sa[6] + sa[7];                            \
        float t4 = sa[8] + sa[9],   t5 = sa[10] + sa[11];                          \
        float t6 = sa[12] + sa[13], t7 = sa[14] + sa[15];                          \
        LSUM += ((t0 + t1) + (t2 + t3)) + ((t4 + t5) + (t6 + t7));                 \
    }                                                                              \
    unsigned u0 = pkbf(sa[0], sa[1]),   u1 = pkbf(sa[2], sa[3]);                   \
    unsigned u2 = pkbf(sa[4], sa[5]),   u3 = pkbf(sa[6], sa[7]);                   \
    unsigned u4 = pkbf(sa[8], sa[9]),   u5 = pkbf(sa[10], sa[11]);                 \
    unsigned u6 = pkbf(sa[12], sa[13]), u7 = pkbf(sa[14], sa[15]);                 \
    asm volatile("v_permlane32_swap_b32 %0, %1" : "+v"(u0), "+v"(u2));             \
    asm volatile("v_permlane32_swap_b32 %0, %1" : "+v"(u1), "+v"(u3));             \
    asm volatile("v_permlane32_swap_b32 %0, %1" : "+v"(u4), "+v"(u6));             \
    asm volatile("v_permlane32_swap_b32 %0, %1" : "+v"(u5), "+v"(u7));             \
    union { unsigned u[4]; short8 v8; } pa0, pa1;                                  \
    pa0.u[0] = u0; pa0.u[1] = u1; pa0.u[2] = u2; pa0.u[3] = u3;                    \
    pa1.u[0] = u4; pa1.u[1] = u5; pa1.u[2] = u6; pa1.u[3] = u7;                    \
    OACC = __builtin_amdgcn_mfma_f32_32x32x16_bf16(pa0.v8, vb0, OACC, 0, 0, 0);    \
    OACC = __builtin_amdgcn_mfma_f32_32x32x16_bf16(pa1.v8, vb1, OACC, 0, 0, 0);    \
} while (0)

static __device__ __forceinline__ void fused_qs(int qp, int s,
                                                const unsigned short* __restrict__ vsb,
                                                const unsigned short* __restrict__ vstb,
                                                const unsigned short* __restrict__ Fb,
                                                float* __restrict__ part,
                                                float* __restrict__ smem, int tid) {
    const int wave = tid >> 6, lane = tid & 63;
    const int hi = lane >> 5, c = lane & 31;

    const int qrow0 = qp * 64 + c;
    short8 q0a = *(const short8*)(Fb + (size_t)qrow0 * 32 + 8 * hi);
    short8 q0b = *(const short8*)(Fb + (size_t)qrow0 * 32 + 16 + 8 * hi);
    short8 q1a = *(const short8*)(Fb + (size_t)(qrow0 + 32) * 32 + 8 * hi);
    short8 q1b = *(const short8*)(Fb + (size_t)(qrow0 + 32) * 32 + 16 + 8 * hi);

    f32x16 oacc0, oacc1;
#pragma unroll
    for (int r = 0; r < 16; ++r) { oacc0[r] = 0.f; oacc1[r] = 0.f; }
    float lsum0 = 0.f, lsum1 = 0.f;

    const int c1 = (125 * (s + 1)) >> 1;
    const unsigned short* vr_base = vsb + (c << 5) + (hi << 3);
    const unsigned short* vt_base = vstb + (c << 5) + (hi << 3);

    for (int ch = ((125 * s) >> 1) + wave; ch < c1; ch += 4) {
        const unsigned short* vrow = vr_base + ((size_t)ch << 10);
        short8 va0 = *(const short8*)(vrow);
        short8 va1 = *(const short8*)(vrow + 16);
        const unsigned short* vtrow = vt_base + ((size_t)ch << 10);
        short8 vb0 = *(const short8*)(vtrow);
        short8 vb1 = *(const short8*)(vtrow + 16);

        TILE(q0a, q0b, oacc0, lsum0);
        TILE(q1a, q1b, oacc1, lsum1);
    }

    lsum0 += __shfl_xor(lsum0, 32, 64);
    lsum1 += __shfl_xor(lsum1, 32, 64);

    // smem: red[2][4][64*17] floats at 0, lred[2][4][32] at 8704
    __syncthreads();
    {
        float* rw0 = smem + (0 * 4 + wave) * 1088 + lane * 17;
        float* rw1 = smem + (1 * 4 + wave) * 1088 + lane * 17;
#pragma unroll
        for (int r = 0; r < 16; ++r) { rw0[r] = oacc0[r]; rw1[r] = oacc1[r]; }
        if (hi == 0) {
            smem[8704 + (0 * 4 + wave) * 32 + c] = lsum0;
            smem[8704 + (1 * 4 + wave) * 32 + c] = lsum1;
        }
    }
    __syncthreads();

#pragma unroll
    for (int t = 0; t < 2; ++t) {
        const size_t pbase = (size_t)((qp * 2 + t) * NSLICE + s) * PART_STRIDE;
        for (int idx = tid; idx < 1024; idx += 256) {
            int ln = idx >> 4, r = idx & 15;
            float sum = smem[(t * 4 + 0) * 1088 + ln * 17 + r] + smem[(t * 4 + 1) * 1088 + ln * 17 + r]
                      + smem[(t * 4 + 2) * 1088 + ln * 17 + r] + smem[(t * 4 + 3) * 1088 + ln * 17 + r];
            int lhi = ln >> 5, lc = ln & 31;
            int q = (r & 3) + 8 * (r >> 2) + 4 * lhi;
            part[pbase + (q << 5) + lc] = sum;
        }
        if (tid < 32)
            part[pbase + 1024 + tid] = smem[8704 + (t * 4 + 0) * 32 + tid] + smem[8704 + (t * 4 + 1) * 32 + tid]
                                     + smem[8704 + (t * 4 + 2) * 32 + tid] + smem[8704 + (t * 4 + 3) * 32 + tid];
    }
}

// ---------------- K1: prep chunks 0..499 + F + zero cnt ----------------
__global__ __launch_bounds__(256)
void prep1_kernel(const float* __restrict__ emb, const float* __restrict__ x,
                  const float* __restrict__ W, const float* __restrict__ bias,
                  const float* __restrict__ temps,
                  unsigned short* __restrict__ vsb, unsigned short* __restrict__ vstb,
                  unsigned short* __restrict__ Fb, int* __restrict__ cnt) {
    const int b = blockIdx.x;
    const int tid = threadIdx.x;
    if (b == 0 && tid < 64) cnt[tid] = 0;
    __shared__ float smem[32 * 33];
    if (b < 500) prep_chunk(b, emb, vsb, vstb, smem, tid);
    else         prep_F(b - 500, x, W, bias, temps, Fb, tid);
}

// ---------------- K2: fused slices 0-7 || prep chunks 500-999 ----------------
__global__ __launch_bounds__(256, 4)
void mixed_kernel(const float* __restrict__ emb,
                  const unsigned short* __restrict__ vsb_c, unsigned short* __restrict__ vsb,
                  const unsigned short* __restrict__ vstb_c, unsigned short* __restrict__ vstb,
                  const unsigned short* __restrict__ Fb, float* __restrict__ part) {
    const int b = blockIdx.x;
    const int tid = threadIdx.x;
    const int s = b & 15, qp = b >> 4;
    __shared__ float smem[8960];
    if (s < 8) {
        fused_qs(qp, s, vsb_c, vstb_c, Fb, part, smem, tid);
    } else {
        int g1 = qp * 8 + (s - 8);
        if (g1 < 500) prep_chunk(500 + g1, emb, vsb, vstb, smem, tid);
    }
}

// ---------------- K3: fused slices 8-15 + cnt-gated combine ----------------
__global__ __launch_bounds__(256, 4)
void finish_kernel(const unsigned short* __restrict__ vsb,
                   const unsigned short* __restrict__ vstb,
                   const unsigned short* __restrict__ Fb,
                   float* __restrict__ part, int* __restrict__ cnt,
                   float* __restrict__ out) {
    const int b = blockIdx.x;            // 512 blocks
    const int tid = threadIdx.x;
    const int s = 8 + (b & 7), qp = b >> 3;
    __shared__ float smem[8960];
    fused_qs(qp, s, vsb, vstb, Fb, part, smem, tid);

    __threadfence();
    __syncthreads();
    __shared__ int sdone;
    if (tid == 0) sdone = (atomicAdd(&cnt[qp], 1) == 7) ? 1 : 0;
    __syncthreads();
    if (sdone) {
        __threadfence();
        for (int t2 = tid; t2 < 2048; t2 += 256) {
            int lr = t2 >> 5, j = t2 & 31;
            int qt = qp * 2 + (lr >> 5), qi = lr & 31;
            float a = 0.f, l = 0.f;
#pragma unroll
            for (int sl = 0; sl < NSLICE; ++sl) {
                const float* p = part + (size_t)(qt * NSLICE + sl) * PART_STRIDE;
                a += p[(qi << 5) + j];
                l += p[1024 + qi];
            }
            out[(size_t)qp * 2048 + t2] = a / l;
        }
    }
}

extern "C" void kernel_launch(void* const* d_in, const int* in_sizes, int n_in,
                              void* d_out, int out_size, void* d_ws, size_t ws_size,
                              hipStream_t stream) {
    const float* x     = (const float*)d_in[0];
    const float* W     = (const float*)d_in[1];
    const float* bias  = (const float*)d_in[2];
    const float* temps = (const float*)d_in[3];
    const float* emb   = (const float*)d_in[4];
    float* out = (float*)d_out;

    char* ws = (char*)d_ws;
    unsigned short* vsb  = (unsigned short*)(ws + OFF_VSB);
    unsigned short* vstb = (unsigned short*)(ws + OFF_VSTB);
    unsigned short* Fb   = (unsigned short*)(ws + OFF_FB);
    float*          part = (float*)(ws + OFF_PART);
    int*            cnt  = (int*)(ws + OFF_CNT);

    prep1_kernel<<<1012, 256, 0, stream>>>(emb, x, W, bias, temps, vsb, vstb, Fb, cnt);
    mixed_kernel<<<1024, 256, 0, stream>>>(emb, vsb, vsb, vstb, vstb, Fb, part);
    finish_kernel<<<512, 256, 0, stream>>>(vsb, vstb, Fb, part, cnt, out);
}

// Round 13
// 69.372 us; speedup vs baseline: 2.3679x; 2.3679x over previous
//
#include <hip/hip_runtime.h>
#include <hip/hip_bf16.h>

// B=2,T=64,V=32000,NH=32,HD=32. BT=128, M=4096 rows, D=32.
// Flash-attn formulation: Q=F (4096x32, pre-scaled by invt*log2e),
// K=V=vs (32000x32). S=Q.vs^T, P=exp2(S), out = P.vs / rowsum(P).
// 4 ordinary launches, overlap via kernel boundaries, NO fences/atomics
// in hot kernels (round-12 lesson: __threadfence in-kernel flushes L2 and
// destroys the vs working set for concurrent blocks -> 4x slowdown):
//  K1: prep chunks 0..499 (slices 0-7) + F                  [HBM]
//  K2: s<8 blocks fused(slice s) || s>=8 blocks prep 500..999 [VALU || HBM]
//  K3: fused slices 8-15                                    [VALU]
//  K4: combine                                              [tiny]
#define NV      32000
#define MROWS   4096
#define NSLICE  16
#define PART_STRIDE 1056       // 32x32 acc + 32 lsum

typedef __attribute__((ext_vector_type(8))) short short8;
typedef __attribute__((ext_vector_type(16))) float f32x16;
typedef __attribute__((ext_vector_type(4))) float f32x4;

// ws layout (bytes):
//   vsb  [NV][32]        bf16 : 0          (2,048,000)
//   vstb [1000][32][32]  bf16 : 2,048,000  (2,048,000)  chunk-blocked transpose
//   Fb   [M][32]         bf16 : 4,096,000  (262,144)
//   part [2048][1056]    f32  : 4,358,144  (8,650,752)
#define OFF_VSB  0
#define OFF_VSTB 2048000
#define OFF_FB   4096000
#define OFF_PART 4358144

static __device__ __forceinline__ unsigned pkbf(float lo, float hi) {
    union { __hip_bfloat162 h; unsigned u; } cv;
    cv.h.x = __float2bfloat16(lo);
    cv.h.y = __float2bfloat16(hi);
    return cv.u;
}
static __device__ __forceinline__ f32x4 ntload(const float* p) {
    return __builtin_nontemporal_load((const f32x4*)p);
}

// ---- prep one 32-v chunk: vs sums -> bf16 vsb + chunk-blocked vstb ----
static __device__ __forceinline__ void prep_chunk(int blk, const float* __restrict__ emb,
                                                  unsigned short* __restrict__ vsb,
                                                  unsigned short* __restrict__ vstb,
                                                  float* __restrict__ smem, int tid) {
    const int vbase = blk * 32;
    const int wave = tid >> 6, lane = tid & 63;
    float (*lds)[33] = (float(*)[33])smem;
    for (int vl = wave; vl < 32; vl += 4) {
        const float* p = emb + (size_t)(vbase + vl) * 1024 + lane * 4;
        f32x4 a0 = ntload(p), a1 = ntload(p + 256), a2 = ntload(p + 512), a3 = ntload(p + 768);
        float s0 = a0.x + a0.y + a0.z + a0.w;
        float s1 = a1.x + a1.y + a1.z + a1.w;
        float s2 = a2.x + a2.y + a2.z + a2.w;
        float s3 = a3.x + a3.y + a3.z + a3.w;
        s0 += __shfl_xor(s0, 1, 64); s0 += __shfl_xor(s0, 2, 64); s0 += __shfl_xor(s0, 4, 64);
        s1 += __shfl_xor(s1, 1, 64); s1 += __shfl_xor(s1, 2, 64); s1 += __shfl_xor(s1, 4, 64);
        s2 += __shfl_xor(s2, 1, 64); s2 += __shfl_xor(s2, 2, 64); s2 += __shfl_xor(s2, 4, 64);
        s3 += __shfl_xor(s3, 1, 64); s3 += __shfl_xor(s3, 2, 64); s3 += __shfl_xor(s3, 4, 64);
        if ((lane & 7) == 0) {
            int hb = lane >> 3;
            lds[vl][hb]      = s0;
            lds[vl][hb + 8]  = s1;
            lds[vl][hb + 16] = s2;
            lds[vl][hb + 24] = s3;
        }
    }
    __syncthreads();
    {
        int v = tid >> 3, h = (tid & 7) * 4;
        unsigned o[2];
        o[0] = pkbf(lds[v][h],     lds[v][h + 1]);
        o[1] = pkbf(lds[v][h + 2], lds[v][h + 3]);
        *(uint2*)(vsb + (size_t)(vbase + v) * 32 + h) = *(uint2*)o;
    }
    {
        int h = tid >> 3, vi = (tid & 7) * 4;
        unsigned o[2];
        o[0] = pkbf(lds[vi][h],     lds[vi + 1][h]);
        o[1] = pkbf(lds[vi + 2][h], lds[vi + 3][h]);
        *(uint2*)(vstb + (size_t)blk * 1024 + h * 32 + vi) = *(uint2*)o;
    }
}

// ---- prep one 256-elem F chunk (pre-scaled by invt*log2e) ----
static __device__ __forceinline__ void prep_F(int fblk, const float* __restrict__ x,
                                              const float* __restrict__ W,
                                              const float* __restrict__ bias,
                                              const float* __restrict__ temps,
                                              unsigned short* __restrict__ Fb, int tid) {
    int t = fblk * 256 + tid;   // t = frow*32 + d
    int frow = t >> 5, d = t & 31;
    const float4* xp = (const float4*)(x + (size_t)frow * 32);
    const float4* wp = (const float4*)(W + (size_t)d * 32);
    float s = bias[d];
#pragma unroll
    for (int i = 0; i < 8; ++i) {
        float4 xv = xp[i];
        float4 wv = wp[i];
        s += xv.x * wv.x + xv.y * wv.y + xv.z * wv.z + xv.w * wv.w;
    }
    float sc = 1.44269504088896f / fmaxf(temps[frow & 31], 0.1f);
    __hip_bfloat16 bv = __float2bfloat16(s * sc);
    Fb[t] = *reinterpret_cast<unsigned short*>(&bv);
}

// ---- fused flash for (qp, s): identical inner loop to round 10 ----
#define TILE(QA, QB, OACC, LSUM) do {                                              \
    f32x16 sa;                                                                     \
    _Pragma("unroll")                                                              \
    for (int r = 0; r < 16; ++r) sa[r] = 0.f;                                      \
    sa = __builtin_amdgcn_mfma_f32_32x32x16_bf16(va0, QA, sa, 0, 0, 0);            \
    sa = __builtin_amdgcn_mfma_f32_32x32x16_bf16(va1, QB, sa, 0, 0, 0);            \
    _Pragma("unroll")                                                              \
    for (int r = 0; r < 16; ++r) sa[r] = __builtin_amdgcn_exp2f(sa[r]);            \
    {                                                                              \
        float t0 = sa[0] + sa[1],   t1 = sa[2] + sa[3];                            \
        float t2 = sa[4] + sa[5],   t3 = sa[6] + sa[7];                            \
        float t4 = sa[8] + sa[9],   t5 = sa[10] + sa[11];                          \
        float t6 = sa[12] + sa[13], t7 = sa[14] + sa[15];                          \
        LSUM += ((t0 + t1) + (t2 + t3)) + ((t4 + t5) + (t6 + t7));                 \
    }                                                                              \
    unsigned u0 = pkbf(sa[0], sa[1]),   u1 = pkbf(sa[2], sa[3]);                   \
    unsigned u2 = pkbf(sa[4], sa[5]),   u3 = pkbf(sa[6], sa[7]);                   \
    unsigned u4 = pkbf(sa[8], sa[9]),   u5 = pkbf(sa[10], sa[11]);                 \
    unsigned u6 = pkbf(sa[12], sa[13]), u7 = pkbf(sa[14], sa[15]);                 \
    asm volatile("v_permlane32_swap_b32 %0, %1" : "+v"(u0), "+v"(u2));             \
    asm volatile("v_permlane32_swap_b32 %0, %1" : "+v"(u1), "+v"(u3));             \
    asm volatile("v_permlane32_swap_b32 %0, %1" : "+v"(u4), "+v"(u6));             \
    asm volatile("v_permlane32_swap_b32 %0, %1" : "+v"(u5), "+v"(u7));             \
    union { unsigned u[4]; short8 v8; } pa0, pa1;                                  \
    pa0.u[0] = u0; pa0.u[1] = u1; pa0.u[2] = u2; pa0.u[3] = u3;                    \
    pa1.u[0] = u4; pa1.u[1] = u5; pa1.u[2] = u6; pa1.u[3] = u7;                    \
    OACC = __builtin_amdgcn_mfma_f32_32x32x16_bf16(pa0.v8, vb0, OACC, 0, 0, 0);    \
    OACC = __builtin_amdgcn_mfma_f32_32x32x16_bf16(pa1.v8, vb1, OACC, 0, 0, 0);    \
} while (0)

static __device__ __forceinline__ void fused_qs(int qp, int s,
                                                const unsigned short* __restrict__ vsb,
                                                const unsigned short* __restrict__ vstb,
                                                const unsigned short* __restrict__ Fb,
                                                float* __restrict__ part,
                                                float* __restrict__ smem, int tid) {
    const int wave = tid >> 6, lane = tid & 63;
    const int hi = lane >> 5, c = lane & 31;

    const int qrow0 = qp * 64 + c;
    short8 q0a = *(const short8*)(Fb + (size_t)qrow0 * 32 + 8 * hi);
    short8 q0b = *(const short8*)(Fb + (size_t)qrow0 * 32 + 16 + 8 * hi);
    short8 q1a = *(const short8*)(Fb + (size_t)(qrow0 + 32) * 32 + 8 * hi);
    short8 q1b = *(const short8*)(Fb + (size_t)(qrow0 + 32) * 32 + 16 + 8 * hi);

    f32x16 oacc0, oacc1;
#pragma unroll
    for (int r = 0; r < 16; ++r) { oacc0[r] = 0.f; oacc1[r] = 0.f; }
    float lsum0 = 0.f, lsum1 = 0.f;

    const int c1 = (125 * (s + 1)) >> 1;
    const unsigned short* vr_base = vsb + (c << 5) + (hi << 3);
    const unsigned short* vt_base = vstb + (c << 5) + (hi << 3);

    for (int ch = ((125 * s) >> 1) + wave; ch < c1; ch += 4) {
        const unsigned short* vrow = vr_base + ((size_t)ch << 10);
        short8 va0 = *(const short8*)(vrow);
        short8 va1 = *(const short8*)(vrow + 16);
        const unsigned short* vtrow = vt_base + ((size_t)ch << 10);
        short8 vb0 = *(const short8*)(vtrow);
        short8 vb1 = *(const short8*)(vtrow + 16);

        TILE(q0a, q0b, oacc0, lsum0);
        TILE(q1a, q1b, oacc1, lsum1);
    }

    lsum0 += __shfl_xor(lsum0, 32, 64);
    lsum1 += __shfl_xor(lsum1, 32, 64);

    // smem: red[2][4][64*17] floats at 0, lred[2][4][32] at 8704
    __syncthreads();
    {
        float* rw0 = smem + (0 * 4 + wave) * 1088 + lane * 17;
        float* rw1 = smem + (1 * 4 + wave) * 1088 + lane * 17;
#pragma unroll
        for (int r = 0; r < 16; ++r) { rw0[r] = oacc0[r]; rw1[r] = oacc1[r]; }
        if (hi == 0) {
            smem[8704 + (0 * 4 + wave) * 32 + c] = lsum0;
            smem[8704 + (1 * 4 + wave) * 32 + c] = lsum1;
        }
    }
    __syncthreads();

#pragma unroll
    for (int t = 0; t < 2; ++t) {
        const size_t pbase = (size_t)((qp * 2 + t) * NSLICE + s) * PART_STRIDE;
        for (int idx = tid; idx < 1024; idx += 256) {
            int ln = idx >> 4, r = idx & 15;
            float sum = smem[(t * 4 + 0) * 1088 + ln * 17 + r] + smem[(t * 4 + 1) * 1088 + ln * 17 + r]
                      + smem[(t * 4 + 2) * 1088 + ln * 17 + r] + smem[(t * 4 + 3) * 1088 + ln * 17 + r];
            int lhi = ln >> 5, lc = ln & 31;
            int q = (r & 3) + 8 * (r >> 2) + 4 * lhi;
            part[pbase + (q << 5) + lc] = sum;
        }
        if (tid < 32)
            part[pbase + 1024 + tid] = smem[8704 + (t * 4 + 0) * 32 + tid] + smem[8704 + (t * 4 + 1) * 32 + tid]
                                     + smem[8704 + (t * 4 + 2) * 32 + tid] + smem[8704 + (t * 4 + 3) * 32 + tid];
    }
}

// ---------------- K1: prep chunks 0..499 + F ----------------
__global__ __launch_bounds__(256)
void prep1_kernel(const float* __restrict__ emb, const float* __restrict__ x,
                  const float* __restrict__ W, const float* __restrict__ bias,
                  const float* __restrict__ temps,
                  unsigned short* __restrict__ vsb, unsigned short* __restrict__ vstb,
                  unsigned short* __restrict__ Fb) {
    const int b = blockIdx.x;
    const int tid = threadIdx.x;
    __shared__ float smem[32 * 33];
    if (b < 500) prep_chunk(b, emb, vsb, vstb, smem, tid);
    else         prep_F(b - 500, x, W, bias, temps, Fb, tid);
}

// ---------------- K2: fused slices 0-7 || prep chunks 500-999 ----------------
__global__ __launch_bounds__(256, 4)
void mixed_kernel(const float* __restrict__ emb,
                  const unsigned short* __restrict__ vsb_c, unsigned short* __restrict__ vsb,
                  const unsigned short* __restrict__ vstb_c, unsigned short* __restrict__ vstb,
                  const unsigned short* __restrict__ Fb, float* __restrict__ part) {
    const int b = blockIdx.x;
    const int tid = threadIdx.x;
    const int s = b & 15, qp = b >> 4;
    __shared__ float smem[8960];
    if (s < 8) {
        fused_qs(qp, s, vsb_c, vstb_c, Fb, part, smem, tid);
    } else {
        int g1 = qp * 8 + (s - 8);
        if (g1 < 500) prep_chunk(500 + g1, emb, vsb, vstb, smem, tid);
    }
}

// ---------------- K3: fused slices 8-15 (plain, no fences) ----------------
__global__ __launch_bounds__(256, 4)
void fused2_kernel(const unsigned short* __restrict__ vsb,
                   const unsigned short* __restrict__ vstb,
                   const unsigned short* __restrict__ Fb,
                   float* __restrict__ part) {
    const int b = blockIdx.x;            // 512 blocks
    const int tid = threadIdx.x;
    const int s = 8 + (b & 7), qp = b >> 3;
    __shared__ float smem[8960];
    fused_qs(qp, s, vsb, vstb, Fb, part, smem, tid);
}

// ---------------- K4: combine slice partials ----------------
__global__ void combine_kernel(const float* __restrict__ part, float* __restrict__ out) {
    int t = blockIdx.x * 256 + threadIdx.x;      // t = qrow*32 + j
    if (t >= MROWS * 32) return;
    int qrow = t >> 5, j = t & 31;
    int qt = qrow >> 5, qi = qrow & 31;
    float a = 0.f, l = 0.f;
#pragma unroll
    for (int s = 0; s < NSLICE; ++s) {
        const float* p = part + (size_t)(qt * NSLICE + s) * PART_STRIDE;
        a += p[(qi << 5) + j];
        l += p[1024 + qi];
    }
    out[t] = a / l;
}

extern "C" void kernel_launch(void* const* d_in, const int* in_sizes, int n_in,
                              void* d_out, int out_size, void* d_ws, size_t ws_size,
                              hipStream_t stream) {
    const float* x     = (const float*)d_in[0];
    const float* W     = (const float*)d_in[1];
    const float* bias  = (const float*)d_in[2];
    const float* temps = (const float*)d_in[3];
    const float* emb   = (const float*)d_in[4];
    float* out = (float*)d_out;

    char* ws = (char*)d_ws;
    unsigned short* vsb  = (unsigned short*)(ws + OFF_VSB);
    unsigned short* vstb = (unsigned short*)(ws + OFF_VSTB);
    unsigned short* Fb   = (unsigned short*)(ws + OFF_FB);
    float*          part = (float*)(ws + OFF_PART);

    prep1_kernel<<<1012, 256, 0, stream>>>(emb, x, W, bias, temps, vsb, vstb, Fb);
    mixed_kernel<<<1024, 256, 0, stream>>>(emb, vsb, vsb, vstb, vstb, Fb, part);
    fused2_kernel<<<512, 256, 0, stream>>>(vsb, vstb, Fb, part);
    combine_kernel<<<(MROWS * 32 + 255) / 256, 256, 0, stream>>>(part, out);
}